// Round 7
// baseline (504.091 us; speedup 1.0000x reference)
//
#include <hip/hip_runtime.h>

#define D 128
#define STAT_SCALE 262144.0f   // 2^18 fixed-point for deterministic int64 stat atomics

typedef _Float16 f16;
typedef f16 f16x8 __attribute__((ext_vector_type(8)));
typedef float f32x4 __attribute__((ext_vector_type(4)));

// ---------- CSR build (adjacency padded to multiple of 8 with zero-row index N) ----------
__global__ __launch_bounds__(256) void k_hist(const int* __restrict__ dst, int* __restrict__ deg, int E) {
    int e = blockIdx.x * 256 + threadIdx.x;
    if (e < E) atomicAdd(&deg[dst[e]], 1);
}

__global__ __launch_bounds__(1024) void k_scan1(const int* __restrict__ deg, int* __restrict__ rowstart,
                                                int* __restrict__ bsum, int N) {
    __shared__ int sd[1024];
    int i = blockIdx.x * 1024 + threadIdx.x;
    int dv = (i < N) ? deg[i] : 0;
    int v = (dv + 7) & ~7;          // padded degree
    sd[threadIdx.x] = v; __syncthreads();
    for (int off = 1; off < 1024; off <<= 1) {
        int t = (threadIdx.x >= off) ? sd[threadIdx.x - off] : 0;
        __syncthreads();
        sd[threadIdx.x] += t;
        __syncthreads();
    }
    if (i < N) rowstart[i] = sd[threadIdx.x] - v;   // exclusive over padded degrees
    if (threadIdx.x == 1023) bsum[blockIdx.x] = sd[1023];
}

__global__ __launch_bounds__(1024) void k_scan2(const int* __restrict__ bsum, int* __restrict__ bofs, int M) {
    __shared__ int sd[1024];
    int v = (threadIdx.x < M) ? bsum[threadIdx.x] : 0;
    sd[threadIdx.x] = v; __syncthreads();
    for (int off = 1; off < 1024; off <<= 1) {
        int t = (threadIdx.x >= off) ? sd[threadIdx.x - off] : 0;
        __syncthreads();
        sd[threadIdx.x] += t;
        __syncthreads();
    }
    if (threadIdx.x < M) bofs[threadIdx.x] = sd[threadIdx.x] - v;  // exclusive
}

// add block offsets AND write the pad entries (zero-row index N)
__global__ __launch_bounds__(1024) void k_scan3(int* rowstart, const int* __restrict__ bofs,
                                                const int* __restrict__ deg, int* __restrict__ csr, int N) {
    int i = blockIdx.x * 1024 + threadIdx.x;
    if (i < N) {
        int rs = rowstart[i] + bofs[blockIdx.x];
        rowstart[i] = rs;
        int d = deg[i], dp = (d + 7) & ~7;
        for (int k = d; k < dp; ++k) csr[rs + k] = N;
    }
}

__global__ __launch_bounds__(256) void k_fill(const int* __restrict__ src, const int* __restrict__ dst,
                                              const int* __restrict__ rowstart, int* __restrict__ cursor,
                                              int* __restrict__ csr, int E) {
    int e = blockIdx.x * 256 + threadIdx.x;
    if (e < E) {
        int d = dst[e];
        int p = atomicAdd(&cursor[d], 1);
        csr[rowstart[d] + p] = src[e];
    }
}

// ---------- x fp32 -> h f16 ----------
__global__ __launch_bounds__(256) void k_cvt(const float* __restrict__ x, f16* __restrict__ o, int n8) {
    int i = blockIdx.x * 256 + threadIdx.x;
    if (i >= n8) return;
    float4 a = ((const float4*)x)[2 * i];
    float4 b = ((const float4*)x)[2 * i + 1];
    f16x8 v;
    v[0] = (f16)a.x; v[1] = (f16)a.y; v[2] = (f16)a.z; v[3] = (f16)a.w;
    v[4] = (f16)b.x; v[5] = (f16)b.y; v[6] = (f16)b.z; v[7] = (f16)b.w;
    ((f16x8*)o)[i] = v;
}

// ---------- W fp32 [k][c] -> pre-swizzled f16 W^T image (LDS-linear) ----------
__global__ __launch_bounds__(256) void k_prepw(const float* __restrict__ W1, const float* __restrict__ W2,
                                               f16* __restrict__ wpre, int L) {
    int idx = blockIdx.x * 256 + threadIdx.x;
    if (idx >= 2 * L * 16384) return;
    int m = idx >> 14, local = idx & 16383;
    int c = local >> 7, r = local & 127;
    int t = r >> 3, j = r & 7;
    int k = ((t ^ (c & 15)) << 3) | j;
    const float* Wsrc = (m < L) ? (W1 + (size_t)m * 16384) : (W2 + (size_t)(m - L) * 16384);
    wpre[idx] = (f16)Wsrc[k * 128 + c];
}

// ---------- z[i] = h[i] + sum_{j in adj(i)} h[j]  (f16 io, fp32 accum) ----------
// 16 threads/row; padded adjacency (x8, zero-row pads) -> branch-free unroll-8:
// 2 contiguous int4 index loads + 8 independent 16B row loads in flight.
__global__ __launch_bounds__(256) void k_gather16(const f16* __restrict__ h, const int* __restrict__ rowstart,
                                                  const int* __restrict__ deg, const int* __restrict__ csr,
                                                  f16* __restrict__ z, int N) {
    int gid = blockIdx.x * 256 + threadIdx.x;
    int node = gid >> 4, ln = gid & 15;
    if (node >= N) return;
    const int ro = ln * 8;
    f16x8 hv = *(const f16x8*)(h + (size_t)node * D + ro);
    float acc[8];
    #pragma unroll
    for (int j = 0; j < 8; ++j) acc[j] = (float)hv[j];
    const int s = rowstart[node];
    const int np = (deg[node] + 7) & ~7;
    for (int k = 0; k < np; k += 8) {
        int4 ja = *(const int4*)(csr + s + k);
        int4 jb = *(const int4*)(csr + s + k + 4);
        f16x8 v0 = *(const f16x8*)(h + (size_t)ja.x * D + ro);
        f16x8 v1 = *(const f16x8*)(h + (size_t)ja.y * D + ro);
        f16x8 v2 = *(const f16x8*)(h + (size_t)ja.z * D + ro);
        f16x8 v3 = *(const f16x8*)(h + (size_t)ja.w * D + ro);
        f16x8 v4 = *(const f16x8*)(h + (size_t)jb.x * D + ro);
        f16x8 v5 = *(const f16x8*)(h + (size_t)jb.y * D + ro);
        f16x8 v6 = *(const f16x8*)(h + (size_t)jb.z * D + ro);
        f16x8 v7 = *(const f16x8*)(h + (size_t)jb.w * D + ro);
        #pragma unroll
        for (int j = 0; j < 8; ++j)
            acc[j] += ((float)v0[j] + (float)v1[j]) + ((float)v2[j] + (float)v3[j])
                    + ((float)v4[j] + (float)v5[j]) + ((float)v6[j] + (float)v7[j]);
    }
    f16x8 o;
    #pragma unroll
    for (int j = 0; j < 8; ++j) o[j] = (f16)acc[j];
    *(f16x8*)(z + (size_t)node * D + ro) = o;
}

// ---------- MFMA GEMM: out[N,128] = f(in)[N,128] @ W[128,128] + bias ----------
// MIN_: 0 = raw f16 A;  1 = A := relu(sc*A + sh), sc/sh from per-layer int64 stats (fused GraphNorm)
// MOUT_: 0 = f16 raw store + int64 fixed-point stat atomics;  1 = f16 relu store;  2 = f32 relu store
// Block: 256 threads / 4 waves; 64 rows/block; each wave 16 rows x 128 cols, acc[8]=32 regs.
template<int MIN_, int MOUT_>
__global__ __launch_bounds__(256, 4) void mfma_gemm(
    const f16* __restrict__ Ain, const f16* __restrict__ Wp,
    const float* __restrict__ bias, const unsigned long long* __restrict__ stats,
    const float* __restrict__ gw, const float* __restrict__ gb, const float* __restrict__ ga,
    void* __restrict__ outp, unsigned long long* __restrict__ statsOut, int N)
{
    __shared__ f16 wlds[16384];     // 32KB W^T swizzled; reused for stats partials + transpose staging
    __shared__ float blds[128];
    __shared__ float sclds[256];

    const int tid = threadIdx.x;
    #pragma unroll
    for (int p = 0; p < 8; ++p)
        ((float4*)wlds)[p * 256 + tid] = ((const float4*)Wp)[p * 256 + tid];
    if (tid < 128) {
        blds[tid] = bias[tid];
        if (MIN_) {
            const float inv = 1.0f / STAT_SCALE;
            float sum = (float)(long long)stats[tid] * inv;
            float sumsq = (float)(long long)stats[128 + tid] * inv;
            float invN = 1.0f / (float)N;
            float m = sum * invN;
            float msq = sumsq * invN;
            float a = ga[tid];
            float var = msq - 2.f * a * m * m + a * a * m * m;
            float sc = gw[tid] * rsqrtf(var + 1e-5f);
            sclds[tid] = sc;
            sclds[128 + tid] = gb[tid] - sc * a * m;
        }
    }
    __syncthreads();

    const int lane = tid & 63, wid = tid >> 6;
    const int l15 = lane & 15, l4 = lane >> 4;
    const int rowA = blockIdx.x * 64 + wid * 16 + l15;
    const size_t arow = (size_t)((rowA < N) ? rowA : (N - 1)) * D;

    // prefetch ALL A fragments (4 x 16B per thread) before the MFMA chain
    f16x8 a[4];
    #pragma unroll
    for (int ks = 0; ks < 4; ++ks)
        a[ks] = *(const f16x8*)(Ain + arow + ks * 32 + l4 * 8);

    if (MIN_) {
        #pragma unroll
        for (int ks = 0; ks < 4; ++ks) {
            const int k0 = ks * 32 + l4 * 8;
            float scv[8], shv[8];
            *(float4*)(scv)     = *(const float4*)(sclds + k0);
            *(float4*)(scv + 4) = *(const float4*)(sclds + k0 + 4);
            *(float4*)(shv)     = *(const float4*)(sclds + 128 + k0);
            *(float4*)(shv + 4) = *(const float4*)(sclds + 128 + k0 + 4);
            #pragma unroll
            for (int j = 0; j < 8; ++j) {
                float v = fmaf((float)a[ks][j], scv[j], shv[j]);
                a[ks][j] = (f16)fmaxf(v, 0.f);
            }
        }
    }

    f32x4 acc[8];
    #pragma unroll
    for (int ct = 0; ct < 8; ++ct) acc[ct] = (f32x4){0.f, 0.f, 0.f, 0.f};

    #pragma unroll
    for (int ks = 0; ks < 4; ++ks) {
        #pragma unroll
        for (int ct = 0; ct < 8; ++ct) {
            const int c = ct * 16 + l15;
            const int sl = (ks * 4 + l4) ^ (c & 15);
            f16x8 b = *(const f16x8*)(wlds + c * D + sl * 8);
            acc[ct] = __builtin_amdgcn_mfma_f32_16x16x32_f16(a[ks], b, acc[ct], 0, 0, 0);
        }
    }

    __syncthreads();   // all W reads done; wlds reusable

    if (MOUT_ == 0) {
        // column stats: intra-wave shfl reduce -> LDS -> cross-wave -> int64 fixed-point atomic
        float* sp = (float*)wlds;
        const int r0 = blockIdx.x * 64 + wid * 16 + l4 * 4;
        #pragma unroll
        for (int ct = 0; ct < 8; ++ct) {
            const int col = ct * 16 + l15;
            const float bv = blds[col];
            float s = 0.f, q = 0.f;
            #pragma unroll
            for (int rg = 0; rg < 4; ++rg) {
                if (r0 + rg < N) {
                    float v = acc[ct][rg] + bv;
                    s += v; q += v * v;
                }
            }
            s += __shfl_xor(s, 16); s += __shfl_xor(s, 32);
            q += __shfl_xor(q, 16); q += __shfl_xor(q, 32);
            if (l4 == 0) { sp[wid * 512 + col] = s; sp[wid * 512 + 128 + col] = q; }
        }
        __syncthreads();
        float v = sp[tid] + sp[512 + tid] + sp[1024 + tid] + sp[1536 + tid];
        long long qv = llrintf(v * STAT_SCALE);
        atomicAdd(&statsOut[tid], (unsigned long long)qv);
        __syncthreads();   // sp reads done before transpose overwrites wlds
    }

    if (MOUT_ < 2) {
        // LDS-transpose epilogue: per-wave [16][136] f16 tile in private 8KB region
        f16* out16 = (f16*)outp;
        f16* tb = wlds + wid * 4096;
        #pragma unroll
        for (int ct = 0; ct < 8; ++ct) {
            const int col = ct * 16 + l15;
            const float bv = blds[col];
            #pragma unroll
            for (int rg = 0; rg < 4; ++rg) {
                float v = acc[ct][rg] + bv;
                if (MOUT_ == 1) v = fmaxf(v, 0.f);
                tb[(l4 * 4 + rg) * 136 + col] = (f16)v;
            }
        }
        // per-wave private region: compiler inserts lgkmcnt waits; no barrier needed
        #pragma unroll
        for (int it = 0; it < 4; ++it) {
            const int lrow = it * 4 + l4;
            const int grow = blockIdx.x * 64 + wid * 16 + lrow;
            f16x8 vv = *(const f16x8*)(tb + lrow * 136 + l15 * 8);
            if (grow < N) *(f16x8*)(out16 + (size_t)grow * D + l15 * 8) = vv;
        }
    } else {
        float* out32 = (float*)outp;
        const int r0 = blockIdx.x * 64 + wid * 16 + l4 * 4;
        #pragma unroll
        for (int ct = 0; ct < 8; ++ct) {
            const int col = ct * 16 + l15;
            const float bv = blds[col];
            #pragma unroll
            for (int rg = 0; rg < 4; ++rg) {
                const int row = r0 + rg;
                if (row < N) out32[(size_t)row * D + col] = fmaxf(acc[ct][rg] + bv, 0.f);
            }
        }
    }
}

extern "C" void kernel_launch(void* const* d_in, const int* in_sizes, int n_in,
                              void* d_out, int out_size, void* d_ws, size_t ws_size,
                              hipStream_t stream) {
    const float* x  = (const float*)d_in[0];
    const int*   ei = (const int*)d_in[1];
    const float* W1 = (const float*)d_in[2];
    const float* b1 = (const float*)d_in[3];
    const float* gw = (const float*)d_in[4];
    const float* gb = (const float*)d_in[5];
    const float* ga = (const float*)d_in[6];
    const float* W2 = (const float*)d_in[7];
    const float* b2 = (const float*)d_in[8];

    const int N = in_sizes[0] / D;
    const int E = in_sizes[1] / 2;
    const int L = in_sizes[2] / (D * D);
    const int* src  = ei;
    const int* dstp = ei + E;

    const int gemmGrid = (N + 63) / 64;

    char* w = (char*)d_ws;
    size_t off = 0;
    f16*   z        = (f16*)(w + off);   off += (size_t)N * D * 2;
    f16*   z2       = (f16*)(w + off);   off += (size_t)N * D * 2;
    f16*   wpre     = (f16*)(w + off);   off += (size_t)2 * L * 16384 * 2;
    int*   deg      = (int*)(w + off);   off += (size_t)N * 4;
    int*   cursor   = (int*)(w + off);   off += (size_t)N * 4;
    int*   rowstart = (int*)(w + off);   off += (size_t)N * 4;
    int*   csr      = (int*)(w + off);   off += ((size_t)E + 8 * (size_t)N) * 4;  // padded
    int*   bsum     = (int*)(w + off);   off += 4096 * 4;
    int*   bofs     = (int*)(w + off);   off += 4096 * 4;
    unsigned long long* statsL = (unsigned long long*)(w + off); off += (size_t)L * 256 * 8;

    f16* h16 = (f16*)d_out;   // intermediate h (f16) in d_out front; final layer overwrites f32
    // zero row at index N for adjacency padding (inside d_out's f16 area, never rewritten)

    const int nsb = (N + 1023) / 1024;
    hipMemsetAsync(deg, 0, (size_t)N * 8, stream);            // deg + cursor (adjacent)
    hipMemsetAsync(statsL, 0, (size_t)L * 256 * 8, stream);
    hipMemsetAsync(h16 + (size_t)N * D, 0, D * 2, stream);    // zero row
    k_hist<<<(E + 255) / 256, 256, 0, stream>>>(dstp, deg, E);
    k_scan1<<<nsb, 1024, 0, stream>>>(deg, rowstart, bsum, N);
    k_scan2<<<1, 1024, 0, stream>>>(bsum, bofs, nsb);
    k_scan3<<<nsb, 1024, 0, stream>>>(rowstart, bofs, deg, csr, N);
    k_fill<<<(E + 255) / 256, 256, 0, stream>>>(src, dstp, rowstart, cursor, csr, E);

    k_cvt<<<((N * D / 8) + 255) / 256, 256, 0, stream>>>(x, h16, N * D / 8);
    k_prepw<<<((2 * L * 16384) + 255) / 256, 256, 0, stream>>>(W1, W2, wpre, L);

    const int gatherGrid = ((size_t)N * 16 + 255) / 256;

    for (int l = 0; l < L; ++l) {
        unsigned long long* st = statsL + (size_t)l * 256;
        k_gather16<<<gatherGrid, 256, 0, stream>>>(h16, rowstart, deg, csr, z, N);
        mfma_gemm<0, 0><<<gemmGrid, 256, 0, stream>>>(
            z, wpre + (size_t)l * 16384, b1 + (size_t)l * D,
            nullptr, nullptr, nullptr, nullptr, z2, st, N);
        if (l < L - 1)
            mfma_gemm<1, 1><<<gemmGrid, 256, 0, stream>>>(
                z2, wpre + (size_t)(L + l) * 16384, b2 + (size_t)l * D,
                st, gw + (size_t)l * D, gb + (size_t)l * D, ga + (size_t)l * D,
                h16, nullptr, N);
        else
            mfma_gemm<1, 2><<<gemmGrid, 256, 0, stream>>>(
                z2, wpre + (size_t)(L + l) * 16384, b2 + (size_t)l * D,
                st, gw + (size_t)l * D, gb + (size_t)l * D, ga + (size_t)l * D,
                d_out, nullptr, N);
    }
}

// Round 8
// 383.449 us; speedup vs baseline: 1.3146x; 1.3146x over previous
//
#include <hip/hip_runtime.h>

#define D 128
#define STAT_SCALE 262144.0f   // 2^18 fixed-point for deterministic int64 stat atomics
#define SLABS 16               // stat atomic slabs (contention 1563 -> ~98 per address)

typedef _Float16 f16;
typedef f16 f16x8 __attribute__((ext_vector_type(8)));
typedef float f32x4 __attribute__((ext_vector_type(4)));

// ---------- CSR build (adjacency padded to multiple of 8 with zero-row index N) ----------
__global__ __launch_bounds__(256) void k_hist(const int* __restrict__ dst, int* __restrict__ deg, int E) {
    int e = blockIdx.x * 256 + threadIdx.x;
    if (e < E) atomicAdd(&deg[dst[e]], 1);
}

__global__ __launch_bounds__(1024) void k_scan1(const int* __restrict__ deg, int* __restrict__ rowstart,
                                                int* __restrict__ bsum, int N) {
    __shared__ int sd[1024];
    int i = blockIdx.x * 1024 + threadIdx.x;
    int dv = (i < N) ? deg[i] : 0;
    int v = (dv + 7) & ~7;          // padded degree
    sd[threadIdx.x] = v; __syncthreads();
    for (int off = 1; off < 1024; off <<= 1) {
        int t = (threadIdx.x >= off) ? sd[threadIdx.x - off] : 0;
        __syncthreads();
        sd[threadIdx.x] += t;
        __syncthreads();
    }
    if (i < N) rowstart[i] = sd[threadIdx.x] - v;   // exclusive over padded degrees
    if (threadIdx.x == 1023) bsum[blockIdx.x] = sd[1023];
}

__global__ __launch_bounds__(1024) void k_scan2(const int* __restrict__ bsum, int* __restrict__ bofs, int M) {
    __shared__ int sd[1024];
    int v = (threadIdx.x < M) ? bsum[threadIdx.x] : 0;
    sd[threadIdx.x] = v; __syncthreads();
    for (int off = 1; off < 1024; off <<= 1) {
        int t = (threadIdx.x >= off) ? sd[threadIdx.x - off] : 0;
        __syncthreads();
        sd[threadIdx.x] += t;
        __syncthreads();
    }
    if (threadIdx.x < M) bofs[threadIdx.x] = sd[threadIdx.x] - v;  // exclusive
}

// add block offsets AND write the pad entries (zero-row index N)
__global__ __launch_bounds__(1024) void k_scan3(int* rowstart, const int* __restrict__ bofs,
                                                const int* __restrict__ deg, int* __restrict__ csr, int N) {
    int i = blockIdx.x * 1024 + threadIdx.x;
    if (i < N) {
        int rs = rowstart[i] + bofs[blockIdx.x];
        rowstart[i] = rs;
        int d = deg[i], dp = (d + 7) & ~7;
        for (int k = d; k < dp; ++k) csr[rs + k] = N;
    }
}

__global__ __launch_bounds__(256) void k_fill(const int* __restrict__ src, const int* __restrict__ dst,
                                              const int* __restrict__ rowstart, int* __restrict__ cursor,
                                              int* __restrict__ csr, int E) {
    int e = blockIdx.x * 256 + threadIdx.x;
    if (e < E) {
        int d = dst[e];
        int p = atomicAdd(&cursor[d], 1);
        csr[rowstart[d] + p] = src[e];
    }
}

// ---------- fused: x fp32 -> h f16  AND  W fp32 -> pre-swizzled f16 image ----------
__global__ __launch_bounds__(256) void k_prep(const float* __restrict__ x, f16* __restrict__ h,
                                              const float* __restrict__ W1, const float* __restrict__ W2,
                                              f16* __restrict__ wpre, int n8, int L) {
    int gid = blockIdx.x * 256 + threadIdx.x;
    if (gid < n8) {
        float4 a = ((const float4*)x)[2 * gid];
        float4 b = ((const float4*)x)[2 * gid + 1];
        f16x8 v;
        v[0] = (f16)a.x; v[1] = (f16)a.y; v[2] = (f16)a.z; v[3] = (f16)a.w;
        v[4] = (f16)b.x; v[5] = (f16)b.y; v[6] = (f16)b.z; v[7] = (f16)b.w;
        ((f16x8*)h)[gid] = v;
        return;
    }
    int idx = gid - n8;
    if (idx >= 2 * L * 16384) return;
    int m = idx >> 14, local = idx & 16383;
    int c = local >> 7, r = local & 127;
    int t = r >> 3, j = r & 7;
    int k = ((t ^ (c & 15)) << 3) | j;
    const float* Wsrc = (m < L) ? (W1 + (size_t)m * 16384) : (W2 + (size_t)(m - L) * 16384);
    wpre[idx] = (f16)Wsrc[k * 128 + c];
}

// ---------- z[i] = h[i] + sum_{j in adj(i)} h[j]  (f16 io, fp32 accum) ----------
// 16 threads/row; padded adjacency (x8, zero-row pads) -> branch-free unroll-8.
__global__ __launch_bounds__(256) void k_gather16(const f16* __restrict__ h, const int* __restrict__ rowstart,
                                                  const int* __restrict__ deg, const int* __restrict__ csr,
                                                  f16* __restrict__ z, int N) {
    int gid = blockIdx.x * 256 + threadIdx.x;
    int node = gid >> 4, ln = gid & 15;
    if (node >= N) return;
    const int ro = ln * 8;
    f16x8 hv = *(const f16x8*)(h + (size_t)node * D + ro);
    float acc[8];
    #pragma unroll
    for (int j = 0; j < 8; ++j) acc[j] = (float)hv[j];
    const int s = rowstart[node];
    const int np = (deg[node] + 7) & ~7;
    for (int k = 0; k < np; k += 8) {
        int4 ja = *(const int4*)(csr + s + k);
        int4 jb = *(const int4*)(csr + s + k + 4);
        f16x8 v0 = *(const f16x8*)(h + (size_t)ja.x * D + ro);
        f16x8 v1 = *(const f16x8*)(h + (size_t)ja.y * D + ro);
        f16x8 v2 = *(const f16x8*)(h + (size_t)ja.z * D + ro);
        f16x8 v3 = *(const f16x8*)(h + (size_t)ja.w * D + ro);
        f16x8 v4 = *(const f16x8*)(h + (size_t)jb.x * D + ro);
        f16x8 v5 = *(const f16x8*)(h + (size_t)jb.y * D + ro);
        f16x8 v6 = *(const f16x8*)(h + (size_t)jb.z * D + ro);
        f16x8 v7 = *(const f16x8*)(h + (size_t)jb.w * D + ro);
        #pragma unroll
        for (int j = 0; j < 8; ++j)
            acc[j] += ((float)v0[j] + (float)v1[j]) + ((float)v2[j] + (float)v3[j])
                    + ((float)v4[j] + (float)v5[j]) + ((float)v6[j] + (float)v7[j]);
    }
    f16x8 o;
    #pragma unroll
    for (int j = 0; j < 8; ++j) o[j] = (f16)acc[j];
    *(f16x8*)(z + (size_t)node * D + ro) = o;
}

// ---------- MFMA GEMM: out[N,128] = f(in)[N,128] @ W[128,128] + bias ----------
// MIN_: 0 = raw f16 A;  1 = A := relu(sc*A + sh), sc/sh from 16-slab int64 stats (fused GraphNorm)
// MOUT_: 0 = f16 raw store + slab int64 stat atomics;  1 = f16 relu store;  2 = f32 relu store
template<int MIN_, int MOUT_>
__global__ __launch_bounds__(256, 4) void mfma_gemm(
    const f16* __restrict__ Ain, const f16* __restrict__ Wp,
    const float* __restrict__ bias, const unsigned long long* __restrict__ stats,
    const float* __restrict__ gw, const float* __restrict__ gb, const float* __restrict__ ga,
    void* __restrict__ outp, unsigned long long* __restrict__ statsOut, int N)
{
    __shared__ f16 wlds[16384];     // 32KB W^T swizzled; reused for stats partials + transpose staging
    __shared__ float blds[128];
    __shared__ float sclds[256];
    __shared__ long long stsum[256];

    const int tid = threadIdx.x;
    #pragma unroll
    for (int p = 0; p < 8; ++p)
        ((float4*)wlds)[p * 256 + tid] = ((const float4*)Wp)[p * 256 + tid];
    if (MIN_) {
        // sum the 16 stat slabs (deterministic integer adds)
        long long acc = 0;
        #pragma unroll
        for (int s = 0; s < SLABS; ++s) acc += (long long)stats[s * 256 + tid];
        stsum[tid] = acc;
    }
    if (tid < 128) blds[tid] = bias[tid];
    __syncthreads();
    if (MIN_ && tid < 128) {
        const float inv = 1.0f / STAT_SCALE;
        float sum = (float)stsum[tid] * inv;
        float sumsq = (float)stsum[128 + tid] * inv;
        float invN = 1.0f / (float)N;
        float m = sum * invN;
        float msq = sumsq * invN;
        float a = ga[tid];
        float var = msq - 2.f * a * m * m + a * a * m * m;
        float sc = gw[tid] * rsqrtf(var + 1e-5f);
        sclds[tid] = sc;
        sclds[128 + tid] = gb[tid] - sc * a * m;
    }
    if (MIN_) __syncthreads();

    const int lane = tid & 63, wid = tid >> 6;
    const int l15 = lane & 15, l4 = lane >> 4;
    const int rowA = blockIdx.x * 64 + wid * 16 + l15;
    const size_t arow = (size_t)((rowA < N) ? rowA : (N - 1)) * D;

    // prefetch ALL A fragments (4 x 16B per thread) before the MFMA chain
    f16x8 a[4];
    #pragma unroll
    for (int ks = 0; ks < 4; ++ks)
        a[ks] = *(const f16x8*)(Ain + arow + ks * 32 + l4 * 8);

    if (MIN_) {
        #pragma unroll
        for (int ks = 0; ks < 4; ++ks) {
            const int k0 = ks * 32 + l4 * 8;
            float scv[8], shv[8];
            *(float4*)(scv)     = *(const float4*)(sclds + k0);
            *(float4*)(scv + 4) = *(const float4*)(sclds + k0 + 4);
            *(float4*)(shv)     = *(const float4*)(sclds + 128 + k0);
            *(float4*)(shv + 4) = *(const float4*)(sclds + 128 + k0 + 4);
            #pragma unroll
            for (int j = 0; j < 8; ++j) {
                float v = fmaf((float)a[ks][j], scv[j], shv[j]);
                a[ks][j] = (f16)fmaxf(v, 0.f);
            }
        }
    }

    f32x4 acc[8];
    #pragma unroll
    for (int ct = 0; ct < 8; ++ct) acc[ct] = (f32x4){0.f, 0.f, 0.f, 0.f};

    #pragma unroll
    for (int ks = 0; ks < 4; ++ks) {
        #pragma unroll
        for (int ct = 0; ct < 8; ++ct) {
            const int c = ct * 16 + l15;
            const int sl = (ks * 4 + l4) ^ (c & 15);
            f16x8 b = *(const f16x8*)(wlds + c * D + sl * 8);
            acc[ct] = __builtin_amdgcn_mfma_f32_16x16x32_f16(a[ks], b, acc[ct], 0, 0, 0);
        }
    }

    __syncthreads();   // all W reads done; wlds reusable

    if (MOUT_ == 0) {
        // column stats: intra-wave shfl reduce -> LDS -> cross-wave -> slab int64 atomic
        float* sp = (float*)wlds;
        const int r0 = blockIdx.x * 64 + wid * 16 + l4 * 4;
        #pragma unroll
        for (int ct = 0; ct < 8; ++ct) {
            const int col = ct * 16 + l15;
            const float bv = blds[col];
            float s = 0.f, q = 0.f;
            #pragma unroll
            for (int rg = 0; rg < 4; ++rg) {
                if (r0 + rg < N) {
                    float v = acc[ct][rg] + bv;
                    s += v; q += v * v;
                }
            }
            s += __shfl_xor(s, 16); s += __shfl_xor(s, 32);
            q += __shfl_xor(q, 16); q += __shfl_xor(q, 32);
            if (l4 == 0) { sp[wid * 512 + col] = s; sp[wid * 512 + 128 + col] = q; }
        }
        __syncthreads();
        float v = sp[tid] + sp[512 + tid] + sp[1024 + tid] + sp[1536 + tid];
        long long qv = llrintf(v * STAT_SCALE);
        atomicAdd(&statsOut[(size_t)(blockIdx.x & (SLABS - 1)) * 256 + tid], (unsigned long long)qv);
        __syncthreads();   // sp reads done before transpose overwrites wlds
    }

    if (MOUT_ < 2) {
        // LDS-transpose epilogue: per-wave [16][136] f16 tile in private 8KB region
        f16* out16 = (f16*)outp;
        f16* tb = wlds + wid * 4096;
        #pragma unroll
        for (int ct = 0; ct < 8; ++ct) {
            const int col = ct * 16 + l15;
            const float bv = blds[col];
            #pragma unroll
            for (int rg = 0; rg < 4; ++rg) {
                float v = acc[ct][rg] + bv;
                if (MOUT_ == 1) v = fmaxf(v, 0.f);
                tb[(l4 * 4 + rg) * 136 + col] = (f16)v;
            }
        }
        #pragma unroll
        for (int it = 0; it < 4; ++it) {
            const int lrow = it * 4 + l4;
            const int grow = blockIdx.x * 64 + wid * 16 + lrow;
            f16x8 vv = *(const f16x8*)(tb + lrow * 136 + l15 * 8);
            if (grow < N) *(f16x8*)(out16 + (size_t)grow * D + l15 * 8) = vv;
        }
    } else {
        float* out32 = (float*)outp;
        const int r0 = blockIdx.x * 64 + wid * 16 + l4 * 4;
        #pragma unroll
        for (int ct = 0; ct < 8; ++ct) {
            const int col = ct * 16 + l15;
            const float bv = blds[col];
            #pragma unroll
            for (int rg = 0; rg < 4; ++rg) {
                const int row = r0 + rg;
                if (row < N) out32[(size_t)row * D + col] = fmaxf(acc[ct][rg] + bv, 0.f);
            }
        }
    }
}

extern "C" void kernel_launch(void* const* d_in, const int* in_sizes, int n_in,
                              void* d_out, int out_size, void* d_ws, size_t ws_size,
                              hipStream_t stream) {
    const float* x  = (const float*)d_in[0];
    const int*   ei = (const int*)d_in[1];
    const float* W1 = (const float*)d_in[2];
    const float* b1 = (const float*)d_in[3];
    const float* gw = (const float*)d_in[4];
    const float* gb = (const float*)d_in[5];
    const float* ga = (const float*)d_in[6];
    const float* W2 = (const float*)d_in[7];
    const float* b2 = (const float*)d_in[8];

    const int N = in_sizes[0] / D;
    const int E = in_sizes[1] / 2;
    const int L = in_sizes[2] / (D * D);
    const int* src  = ei;
    const int* dstp = ei + E;

    const int gemmGrid = (N + 63) / 64;

    char* w = (char*)d_ws;
    size_t off = 0;
    f16*   z        = (f16*)(w + off);   off += (size_t)N * D * 2;
    f16*   z2       = (f16*)(w + off);   off += (size_t)N * D * 2;
    f16*   wpre     = (f16*)(w + off);   off += (size_t)2 * L * 16384 * 2;
    int*   deg      = (int*)(w + off);   off += (size_t)N * 4;
    int*   cursor   = (int*)(w + off);   off += (size_t)N * 4;
    int*   rowstart = (int*)(w + off);   off += (size_t)N * 4;
    int*   csr      = (int*)(w + off);   off += ((size_t)E + 8 * (size_t)N) * 4;  // padded
    int*   bsum     = (int*)(w + off);   off += 4096 * 4;
    int*   bofs     = (int*)(w + off);   off += 4096 * 4;
    unsigned long long* statsL = (unsigned long long*)(w + off); off += (size_t)L * SLABS * 256 * 8;

    f16* h16 = (f16*)d_out;   // intermediate h (f16) in d_out front; final layer overwrites f32
    // zero row at index N for adjacency padding (inside d_out's f16 area, never rewritten)

    const int nsb = (N + 1023) / 1024;
    hipMemsetAsync(deg, 0, (size_t)N * 8, stream);                 // deg + cursor (adjacent)
    hipMemsetAsync(statsL, 0, (size_t)L * SLABS * 256 * 8, stream);
    hipMemsetAsync(h16 + (size_t)N * D, 0, D * 2, stream);         // zero row
    k_hist<<<(E + 255) / 256, 256, 0, stream>>>(dstp, deg, E);
    k_scan1<<<nsb, 1024, 0, stream>>>(deg, rowstart, bsum, N);
    k_scan2<<<1, 1024, 0, stream>>>(bsum, bofs, nsb);
    k_scan3<<<nsb, 1024, 0, stream>>>(rowstart, bofs, deg, csr, N);
    k_fill<<<(E + 255) / 256, 256, 0, stream>>>(src, dstp, rowstart, cursor, csr, E);

    const int n8 = N * D / 8;
    const int prepTotal = n8 + 2 * L * 16384;
    k_prep<<<(prepTotal + 255) / 256, 256, 0, stream>>>(x, h16, W1, W2, wpre, n8, L);

    const int gatherGrid = ((size_t)N * 16 + 255) / 256;

    for (int l = 0; l < L; ++l) {
        unsigned long long* st = statsL + (size_t)l * SLABS * 256;
        k_gather16<<<gatherGrid, 256, 0, stream>>>(h16, rowstart, deg, csr, z, N);
        mfma_gemm<0, 0><<<gemmGrid, 256, 0, stream>>>(
            z, wpre + (size_t)l * 16384, b1 + (size_t)l * D,
            nullptr, nullptr, nullptr, nullptr, z2, st, N);
        if (l < L - 1)
            mfma_gemm<1, 1><<<gemmGrid, 256, 0, stream>>>(
                z2, wpre + (size_t)(L + l) * 16384, b2 + (size_t)l * D,
                st, gw + (size_t)l * D, gb + (size_t)l * D, ga + (size_t)l * D,
                h16, nullptr, N);
        else
            mfma_gemm<1, 2><<<gemmGrid, 256, 0, stream>>>(
                z2, wpre + (size_t)(L + l) * 16384, b2 + (size_t)l * D,
                st, gw + (size_t)l * D, gb + (size_t)l * D, ga + (size_t)l * D,
                d_out, nullptr, N);
    }
}